// Round 7
// baseline (309.100 us; speedup 1.0000x reference)
//
#include <hip/hip_runtime.h>
#include <hip/hip_bf16.h>
#include <math.h>

// MambaBlock v7: direct-from-global MFMA frags (no-LDS operands where rows are
// block-unique), reordered wcat for in-lane SSM epilogue, packed bf16 (BX,C),
// chunk-16 scan, fine grids everywhere. No workspace aliasing (plenty of room).

#define DEV static __device__ __forceinline__

constexpr int Bn = 8, Dm = 192, Ln = 4096, Sn = 64, Hd = 768;

typedef __attribute__((ext_vector_type(8))) short bf16x8;
typedef __attribute__((ext_vector_type(4))) float f32x4;

DEV float wave_sum(float v) {
#pragma unroll
  for (int off = 1; off < 64; off <<= 1) v += __shfl_xor(v, off);
  return v;
}

DEV short f2b(float x) {
  __hip_bfloat16 h = __float2bfloat16(x);
  return *(short*)&h;
}

DEV float b2f(short x) {
  __hip_bfloat16 h = *(__hip_bfloat16*)&x;
  return __bfloat162float(h);
}

// ---- K1/K9 shared shape: transpose + LN, l-tile 32, grid (128, 8) ----------
__global__ __launch_bounds__(256) void k_ln(
    const float* __restrict__ x, const float* __restrict__ g1, const float* __restrict__ b1,
    const float* __restrict__ g2, const float* __restrict__ b2,
    short* __restrict__ xnb, short* __restrict__ xln1b) {
  __shared__ __align__(16) float tile[Dm * 33];
  int b = blockIdx.y, l0 = blockIdx.x * 32, tid = threadIdx.x;
  const float* xb = x + (size_t)b * Dm * Ln;
  for (int i = tid; i < Dm * 8; i += 256) {
    int d = i >> 3, l4 = (i & 7) << 2;
    float4 v = *(const float4*)&xb[d * Ln + l0 + l4];
    tile[d * 33 + l4]     = v.x; tile[d * 33 + l4 + 1] = v.y;
    tile[d * 33 + l4 + 2] = v.z; tile[d * 33 + l4 + 3] = v.w;
  }
  __syncthreads();
  int lane = tid & 63, wv = tid >> 6;
  float ga0 = g1[lane], ga1 = g1[lane + 64], ga2 = g1[lane + 128];
  float bb0 = b1[lane], bb1 = b1[lane + 64], bb2 = b1[lane + 128];
  float gc0 = g2[lane], gc1 = g2[lane + 64], gc2 = g2[lane + 128];
  float bc0 = b2[lane], bc1 = b2[lane + 64], bc2 = b2[lane + 128];
  for (int li = wv; li < 32; li += 4) {
    float v0 = tile[lane * 33 + li], v1 = tile[(lane + 64) * 33 + li], v2 = tile[(lane + 128) * 33 + li];
    float s  = wave_sum(v0 + v1 + v2);
    float sq = wave_sum(v0 * v0 + v1 * v1 + v2 * v2);
    float m = s * (1.f / 192.f);
    float inv = rsqrtf(sq * (1.f / 192.f) - m * m + 1e-5f);
    float y0 = (v0 - m) * inv * ga0 + bb0;
    float y1 = (v1 - m) * inv * ga1 + bb1;
    float y2 = (v2 - m) * inv * ga2 + bb2;
    float s2  = wave_sum(y0 + y1 + y2);
    float sq2 = wave_sum(y0 * y0 + y1 * y1 + y2 * y2);
    float m2 = s2 * (1.f / 192.f);
    float inv2 = rsqrtf(sq2 * (1.f / 192.f) - m2 * m2 + 1e-5f);
    size_t base = ((size_t)b * Ln + l0 + li) * Dm;
    xln1b[base + lane]       = f2b(y0);
    xln1b[base + lane + 64]  = f2b(y1);
    xln1b[base + lane + 128] = f2b(y2);
    xnb[base + lane]       = f2b((y0 - m2) * inv2 * gc0 + bc0);
    xnb[base + lane + 64]  = f2b((y1 - m2) * inv2 * gc1 + bc1);
    xnb[base + lane + 128] = f2b((y2 - m2) * inv2 * gc2 + bc2);
  }
}

// ---- K2: weights -> bf16; wcat rows PERMUTED for in-lane proj epilogue -----
// wcat row r = (s>>5)*128 + (mat*2 + ((s>>4)&1))*16 + (s&15)
__global__ __launch_bounds__(256) void k_wconv(
    const float* __restrict__ dt_w, const float* __restrict__ B_w,
    const float* __restrict__ C_w, const float* __restrict__ xp_w,
    const float* __restrict__ out_w, const float* __restrict__ w1,
    const float* __restrict__ w2, short* __restrict__ wb) {
  int i = blockIdx.x * 256 + threadIdx.x;  // 89088 float4 groups total
  if (i >= 89088) return;
  if (i < 12288) {
    int mat = i / 3072, rem = i % 3072;
    int s = rem / 48, c4 = rem % 48;
    const float4* src = (mat == 0) ? (const float4*)dt_w
                      : (mat == 1) ? (const float4*)B_w
                      : (mat == 2) ? (const float4*)C_w : (const float4*)xp_w;
    float4 v = src[rem];
    int r = (s >> 5) * 128 + (mat * 2 + ((s >> 4) & 1)) * 16 + (s & 15);
    int o = r * 192 + c4 * 4;
    wb[o] = f2b(v.x); wb[o + 1] = f2b(v.y); wb[o + 2] = f2b(v.z); wb[o + 3] = f2b(v.w);
    return;
  }
  const float4* src;
  if (i < 15360)      src = (const float4*)out_w + (i - 12288);
  else if (i < 52224) src = (const float4*)w1 + (i - 15360);
  else                src = (const float4*)w2 + (i - 52224);
  float4 v = *src;
  int o = i * 4;
  wb[o] = f2b(v.x); wb[o + 1] = f2b(v.y); wb[o + 2] = f2b(v.z); wb[o + 3] = f2b(v.w);
}

// ---- K3: MFMA proj (m-tile 32, A direct-global, grid 1024 = 4/CU) ----------
__global__ __launch_bounds__(256) void k_proj(
    const short* __restrict__ xnb, const short* __restrict__ wcat,
    const float* __restrict__ dt_b, const float* __restrict__ xp_b,
    const float* __restrict__ A_log, float* __restrict__ aA, unsigned* __restrict__ bxc) {
  __shared__ __align__(16) short Bs[256 * 72];
  int m0 = blockIdx.x * 32, tid = threadIdx.x;
  int lane = tid & 63, l16 = lane & 15, quad = lane >> 4;
  int wm = (tid >> 6) >> 1, wn = (tid >> 6) & 1;
  f32x4 acc[8] = {};
  for (int kt = 0; kt < 3; kt++) {
    int kb = kt * 64;
    for (int i = tid; i < 2048; i += 256) {
      int row = i >> 3, c8 = (i & 7) * 8;
      *(float4*)&Bs[row * 72 + c8] = *(const float4*)&wcat[row * 192 + kb + c8];
    }
    __syncthreads();
#pragma unroll
    for (int ks = 0; ks < 2; ks++) {
      int ko = ks * 32 + quad * 8;
      bf16x8 a0 = *(const bf16x8*)&xnb[(size_t)(m0 + wm * 16 + l16) * 192 + kb + ko];
#pragma unroll
      for (int j = 0; j < 8; j++) {
        bf16x8 bf = *(const bf16x8*)&Bs[(wn * 128 + j * 16 + l16) * 72 + ko];
        acc[j] = __builtin_amdgcn_mfma_f32_16x16x32_bf16(a0, bf, acc[j], 0, 0, 0);
      }
    }
    __syncthreads();
  }
  float Av[2], dtbv[2], xpbv[2];
#pragma unroll
  for (int sub = 0; sub < 2; sub++) {
    int s = wn * 32 + sub * 16 + l16;
    Av[sub] = -expf(A_log[s]); dtbv[sub] = dt_b[s]; xpbv[sub] = xp_b[s];
  }
#pragma unroll
  for (int r = 0; r < 4; r++) {
    int m = m0 + wm * 16 + quad * 4 + r;
#pragma unroll
    for (int sub = 0; sub < 2; sub++) {
      int s = wn * 32 + sub * 16 + l16;
      float z = acc[0 + sub][r] + dtbv[sub];
      float sp = (z > 20.f) ? z : log1pf(expf(z));
      float delta = sp * 0.01f + 0.0001f;
      float bt  = acc[2 + sub][r];
      float ct  = acc[4 + sub][r];
      float xpv = acc[6 + sub][r] + xpbv[sub];
      float dA = fminf(fmaxf(delta * Av[sub], -10.f), -0.0001f);
      float Ae = fminf(fmaxf(expf(dA), 0.001f), 0.999f) + 1e-10f;
      aA[(size_t)m * 64 + s] = Ae;
      unsigned pk = (unsigned)(unsigned short)f2b(delta * bt * xpv)
                  | ((unsigned)(unsigned short)f2b(ct) << 16);
      bxc[(size_t)m * 64 + s] = pk;
    }
  }
}

// ---- K4: scan phase 1 (16-step chunks, grid (256,8) = 8 waves/CU) ----------
__global__ __launch_bounds__(64) void k_scan1(const float* __restrict__ aA,
                                              const unsigned* __restrict__ bxc,
                                              float* __restrict__ sums) {
  int c = blockIdx.x, b = blockIdx.y, s = threadIdx.x;
  size_t r0 = (size_t)b * Ln + c * 16;
  const float* ap = aA + r0 * 64;
  const unsigned* bp = bxc + r0 * 64;
  float prodA = 1.f, h = 0.f;
  int t = 0;
  if (c == 0) { prodA = ap[s]; h = b2f((short)(bp[s] & 0xFFFF)); t = 1; }
#pragma unroll 4
  for (; t < 16; t++) {
    float a = ap[t * 64 + s];
    float bx = b2f((short)(bp[t * 64 + s] & 0xFFFF));
    h = a * (h + bx);
    prodA *= a;
  }
  int ci = b * 256 + c;
  sums[(ci * 2 + 0) * 64 + s] = prodA;
  sums[(ci * 2 + 1) * 64 + s] = h;
}

// ---- K5: scan phase 2 (carry chain over 256 chunks), one block per batch ---
__global__ __launch_bounds__(64) void k_scan2(const float* __restrict__ sums, float* __restrict__ carries) {
  int b = blockIdx.x, s = threadIdx.x;
  float cur = 0.f;
#pragma unroll 4
  for (int c = 0; c < 256; c++) {
    int ci = b * 256 + c;
    carries[ci * 64 + s] = cur;
    cur = sums[(ci * 2 + 0) * 64 + s] * cur + sums[(ci * 2 + 1) * 64 + s];
  }
}

// ---- K6: scan phase 3 (replay, y = C*h -> bf16) ----------------------------
__global__ __launch_bounds__(64) void k_scan3(const float* __restrict__ aA,
                                              const unsigned* __restrict__ bxc,
                                              const float* __restrict__ carries,
                                              short* __restrict__ y) {
  int c = blockIdx.x, b = blockIdx.y, s = threadIdx.x;
  size_t r0 = (size_t)b * Ln + c * 16;
  const float* ap = aA + r0 * 64;
  const unsigned* bp = bxc + r0 * 64;
  short* yo = y + r0 * 64;
  float h = carries[(b * 256 + c) * 64 + s];
  int t = 0;
  if (c == 0) {
    unsigned u = bp[s];
    h = b2f((short)(u & 0xFFFF));
    yo[s] = f2b(b2f((short)(u >> 16)) * h);
    t = 1;
  }
#pragma unroll 4
  for (; t < 16; t++) {
    unsigned u = bp[t * 64 + s];
    float a = ap[t * 64 + s];
    h = a * (h + b2f((short)(u & 0xFFFF)));
    yo[t * 64 + s] = f2b(b2f((short)(u >> 16)) * h);
  }
}

// ---- K7: MFMA out-proj (weights in LDS, y frags direct; grid (512,2)) ------
__global__ __launch_bounds__(256) void k_out(
    const short* __restrict__ y, const short* __restrict__ owb, const float* __restrict__ out_b,
    const float* __restrict__ Dp, const short* __restrict__ xln1b, float* __restrict__ sout) {
  __shared__ __align__(16) short As[96 * 72];
  int l0g = blockIdx.x * 64, d0 = blockIdx.y * 96, tid = threadIdx.x;
  int lane = tid & 63, l16 = lane & 15, quad = lane >> 4;
  int wm = (tid >> 6) >> 1, wn = (tid >> 6) & 1;
  f32x4 acc[3][2] = {};
  for (int i = tid; i < 768; i += 256) {
    int row = i >> 3, c8 = (i & 7) * 8;
    *(float4*)&As[row * 72 + c8] = *(const float4*)&owb[(d0 + row) * 64 + c8];
  }
  __syncthreads();
#pragma unroll
  for (int ks = 0; ks < 2; ks++) {
    int ko = ks * 32 + quad * 8;
    bf16x8 a[3], b[2];
#pragma unroll
    for (int mi = 0; mi < 3; mi++) a[mi] = *(const bf16x8*)&As[(wm * 48 + mi * 16 + l16) * 72 + ko];
#pragma unroll
    for (int ni = 0; ni < 2; ni++)
      b[ni] = *(const bf16x8*)&y[(size_t)(l0g + wn * 32 + ni * 16 + l16) * 64 + ko];
#pragma unroll
    for (int mi = 0; mi < 3; mi++)
#pragma unroll
      for (int ni = 0; ni < 2; ni++)
        acc[mi][ni] = __builtin_amdgcn_mfma_f32_16x16x32_bf16(a[mi], b[ni], acc[mi][ni], 0, 0, 0);
  }
  int bb = l0g >> 12;
#pragma unroll
  for (int mi = 0; mi < 3; mi++)
#pragma unroll
    for (int r = 0; r < 4; r++) {
      int d = d0 + wm * 48 + mi * 16 + quad * 4 + r;
      float ob = out_b[d];
      float dc = fminf(fmaxf(Dp[d], -2.f), 2.f);
#pragma unroll
      for (int ni = 0; ni < 2; ni++) {
        int l = l0g + wn * 32 + ni * 16 + l16;
        float v = acc[mi][ni][r] + ob;
        if (dc != 0.f) v += dc * b2f(xln1b[(size_t)l * 192 + d]);
        sout[((size_t)bb * Dm + d) * Ln + (l & 4095)] = v;
      }
    }
}

// ---- K8: depthwise conv 3x3 + BN + residual combine -> xr (NCHW) -----------
__global__ __launch_bounds__(256) void k_conv(
    const float* __restrict__ x, const float* __restrict__ dw,
    const float* __restrict__ bn_g, const float* __restrict__ bn_b,
    const float* __restrict__ bn_rm, const float* __restrict__ bn_rv,
    const float* __restrict__ sout, const float* __restrict__ a_loc,
    const float* __restrict__ a_ssm, float* __restrict__ xr) {
  __shared__ __align__(16) float xs[64 * 64];
  int d = blockIdx.x, b = blockIdx.y, tid = threadIdx.x;
  const float* xp = x + ((size_t)b * Dm + d) * Ln;
  for (int i = tid; i < 1024; i += 256) ((float4*)xs)[i] = ((const float4*)xp)[i];
  __syncthreads();
  float w[9];
#pragma unroll
  for (int k = 0; k < 9; k++) w[k] = dw[d * 9 + k];
  float scale = bn_g[d] * rsqrtf(bn_rv[d] + 1e-5f);
  float rm = bn_rm[d], bb = bn_b[d];
  float al = a_loc[0], as_ = a_ssm[0];
  const float* sp = sout + ((size_t)b * Dm + d) * Ln;
  float* xo = xr + ((size_t)b * Dm + d) * Ln;
  for (int i = tid; i < 4096; i += 256) {
    int h = i >> 6, wc = i & 63;
    float acc = 0.f;
#pragma unroll
    for (int kh = 0; kh < 3; kh++) {
      int hh = h + kh - 1;
      if (hh < 0 || hh >= 64) continue;
#pragma unroll
      for (int kw = 0; kw < 3; kw++) {
        int ww2 = wc + kw - 1;
        if (ww2 < 0 || ww2 >= 64) continue;
        acc += xs[hh * 64 + ww2] * w[kh * 3 + kw];
      }
    }
    float xl = (acc - rm) * scale + bb;
    xo[i] = xs[i] + al * xl + as_ * sp[i];
  }
}

// ---- K9: ln2 -> bf16 xn2, l-tile 32, grid (128,8) --------------------------
__global__ __launch_bounds__(256) void k_ln2(
    const float* __restrict__ xr, const float* __restrict__ g, const float* __restrict__ bb,
    short* __restrict__ xn2) {
  __shared__ __align__(16) float tile[Dm * 33];
  int b = blockIdx.y, l0 = blockIdx.x * 32, tid = threadIdx.x;
  const float* xb = xr + (size_t)b * Dm * Ln;
  for (int i = tid; i < Dm * 8; i += 256) {
    int d = i >> 3, l4 = (i & 7) << 2;
    float4 v = *(const float4*)&xb[d * Ln + l0 + l4];
    tile[d * 33 + l4]     = v.x; tile[d * 33 + l4 + 1] = v.y;
    tile[d * 33 + l4 + 2] = v.z; tile[d * 33 + l4 + 3] = v.w;
  }
  __syncthreads();
  int lane = tid & 63, wv = tid >> 6;
  float g0 = g[lane], g1v = g[lane + 64], g2v = g[lane + 128];
  float b0 = bb[lane], b1v = bb[lane + 64], b2v = bb[lane + 128];
  for (int li = wv; li < 32; li += 4) {
    float v0 = tile[lane * 33 + li], v1 = tile[(lane + 64) * 33 + li], v2 = tile[(lane + 128) * 33 + li];
    float s  = wave_sum(v0 + v1 + v2);
    float sq = wave_sum(v0 * v0 + v1 * v1 + v2 * v2);
    float m = s * (1.f / 192.f);
    float inv = rsqrtf(sq * (1.f / 192.f) - m * m + 1e-5f);
    size_t base = ((size_t)b * Ln + l0 + li) * Dm;
    xn2[base + lane]       = f2b((v0 - m) * inv * g0 + b0);
    xn2[base + lane + 64]  = f2b((v1 - m) * inv * g1v + b1v);
    xn2[base + lane + 128] = f2b((v2 - m) * inv * g2v + b2v);
  }
}

// ---- K10: MFMA GEMM1 (A direct-global, Bs LDS, Cs-staged coalesced out) ----
__global__ __launch_bounds__(256) void k_gemm1(
    const short* __restrict__ xn2, const short* __restrict__ w1b,
    const float* __restrict__ b1h, short* __restrict__ hid) {
  __shared__ __align__(16) short smem[128 * 136];  // Bs (128*72) | Cs (128*136) overlap
  short* Bs = smem;
  int m0 = blockIdx.x * 128, n0 = blockIdx.y * 128, tid = threadIdx.x;
  int lane = tid & 63, l16 = lane & 15, quad = lane >> 4;
  int wm = (tid >> 6) >> 1, wn = (tid >> 6) & 1;
  f32x4 acc[4][4] = {};
  for (int kt = 0; kt < 3; kt++) {
    int kb = kt * 64;
    for (int i = tid; i < 1024; i += 256) {
      int row = i >> 3, c8 = (i & 7) * 8;
      *(float4*)&Bs[row * 72 + c8] = *(const float4*)&w1b[(size_t)(n0 + row) * 192 + kb + c8];
    }
    __syncthreads();
#pragma unroll
    for (int ks = 0; ks < 2; ks++) {
      int ko = ks * 32 + quad * 8;
      bf16x8 a[4], b[4];
#pragma unroll
      for (int mi = 0; mi < 4; mi++)
        a[mi] = *(const bf16x8*)&xn2[(size_t)(m0 + wm * 64 + mi * 16 + l16) * 192 + kb + ko];
#pragma unroll
      for (int ni = 0; ni < 4; ni++) b[ni] = *(const bf16x8*)&Bs[(wn * 64 + ni * 16 + l16) * 72 + ko];
#pragma unroll
      for (int mi = 0; mi < 4; mi++)
#pragma unroll
        for (int ni = 0; ni < 4; ni++)
          acc[mi][ni] = __builtin_amdgcn_mfma_f32_16x16x32_bf16(a[mi], b[ni], acc[mi][ni], 0, 0, 0);
    }
    __syncthreads();
  }
  short* Cs = smem;
  float bias4[4];
#pragma unroll
  for (int ni = 0; ni < 4; ni++) bias4[ni] = b1h[n0 + wn * 64 + ni * 16 + l16];
#pragma unroll
  for (int mi = 0; mi < 4; mi++)
#pragma unroll
    for (int ni = 0; ni < 4; ni++) {
      int n = wn * 64 + ni * 16 + l16;
#pragma unroll
      for (int r = 0; r < 4; r++) {
        int m = wm * 64 + mi * 16 + quad * 4 + r;
        float v = acc[mi][ni][r] + bias4[ni];
        float g = 0.5f * v * (1.f + erff(v * 0.70710678118f));
        Cs[m * 136 + n] = f2b(g);
      }
    }
  __syncthreads();
  for (int i = tid; i < 2048; i += 256) {
    int m = i >> 4, ch = i & 15;
    *(float4*)&hid[(size_t)(m0 + m) * 768 + n0 + ch * 8] = *(const float4*)&Cs[m * 136 + ch * 8];
  }
}

// ---- K11: MFMA GEMM2 (Wt LDS, hid frags direct; grid (512,2)) --------------
__global__ __launch_bounds__(256) void k_gemm2(
    const short* __restrict__ hid, const short* __restrict__ w2b,
    const float* __restrict__ b2o, const float* __restrict__ xr,
    const float* __restrict__ am, float* __restrict__ out) {
  __shared__ __align__(16) short Wt[96 * 72];
  int l0g = blockIdx.x * 64, d0 = blockIdx.y * 96, tid = threadIdx.x;
  int lane = tid & 63, l16 = lane & 15, quad = lane >> 4;
  int wm = (tid >> 6) >> 1, wn = (tid >> 6) & 1;
  f32x4 acc[3][2] = {};
  for (int kt = 0; kt < 12; kt++) {
    int kb = kt * 64;
    for (int i = tid; i < 768; i += 256) {
      int row = i >> 3, c8 = (i & 7) * 8;
      *(float4*)&Wt[row * 72 + c8] = *(const float4*)&w2b[(size_t)(d0 + row) * 768 + kb + c8];
    }
    __syncthreads();
#pragma unroll
    for (int ks = 0; ks < 2; ks++) {
      int ko = ks * 32 + quad * 8;
      bf16x8 a[3], b[2];
#pragma unroll
      for (int mi = 0; mi < 3; mi++) a[mi] = *(const bf16x8*)&Wt[(wm * 48 + mi * 16 + l16) * 72 + ko];
#pragma unroll
      for (int ni = 0; ni < 2; ni++)
        b[ni] = *(const bf16x8*)&hid[(size_t)(l0g + wn * 32 + ni * 16 + l16) * 768 + kb + ko];
#pragma unroll
      for (int mi = 0; mi < 3; mi++)
#pragma unroll
        for (int ni = 0; ni < 2; ni++)
          acc[mi][ni] = __builtin_amdgcn_mfma_f32_16x16x32_bf16(a[mi], b[ni], acc[mi][ni], 0, 0, 0);
    }
    __syncthreads();
  }
  float alpha = am[0];
#pragma unroll
  for (int mi = 0; mi < 3; mi++)
#pragma unroll
    for (int r = 0; r < 4; r++) {
      int d = d0 + wm * 48 + mi * 16 + quad * 4 + r;
      float bias = b2o[d];
#pragma unroll
      for (int ni = 0; ni < 2; ni++) {
        int lg = l0g + wn * 32 + ni * 16 + l16;
        size_t idx = ((size_t)(lg >> 12) * Dm + d) * Ln + (lg & 4095);
        out[idx] = xr[idx] + alpha * (acc[mi][ni][r] + bias);
      }
    }
}

extern "C" void kernel_launch(void* const* d_in, const int* in_sizes, int n_in,
                              void* d_out, int out_size, void* d_ws, size_t ws_size,
                              hipStream_t stream) {
  (void)in_sizes; (void)n_in; (void)out_size; (void)ws_size;
  const float* x     = (const float*)d_in[0];
  const float* ln1_g = (const float*)d_in[1];
  const float* ln1_b = (const float*)d_in[2];
  const float* ln2_g = (const float*)d_in[3];
  const float* ln2_b = (const float*)d_in[4];
  const float* dw_w  = (const float*)d_in[5];
  const float* bn_g  = (const float*)d_in[6];
  const float* bn_b  = (const float*)d_in[7];
  const float* bn_rm = (const float*)d_in[8];
  const float* bn_rv = (const float*)d_in[9];
  const float* ssm_g = (const float*)d_in[10];
  const float* ssm_b = (const float*)d_in[11];
  const float* xp_w  = (const float*)d_in[12];
  const float* xp_b  = (const float*)d_in[13];
  const float* dt_w  = (const float*)d_in[14];
  const float* dt_b  = (const float*)d_in[15];
  const float* A_log = (const float*)d_in[16];
  const float* B_w   = (const float*)d_in[17];
  const float* C_w   = (const float*)d_in[18];
  const float* Dp    = (const float*)d_in[19];
  const float* out_w = (const float*)d_in[20];
  const float* out_b = (const float*)d_in[21];
  const float* w1    = (const float*)d_in[22];
  const float* b1    = (const float*)d_in[23];
  const float* w2    = (const float*)d_in[24];
  const float* b2    = (const float*)d_in[25];
  const float* a_loc = (const float*)d_in[26];
  const float* a_ssm = (const float*)d_in[27];
  const float* a_mlp = (const float*)d_in[28];

  float* ws = (float*)d_ws;
  short*    xnb   = (short*)ws;                       // [32768,192] bf16
  short*    xln1b = (short*)(ws + 3145728);           // [32768,192] bf16
  float*    aA    = ws + 6291456;                     // [32768,64] f32
  unsigned* bxc   = (unsigned*)(ws + 8388608);        // [32768,64] packed bf16x2
  short*    yB    = (short*)(ws + 10485760);          // [32768,64] bf16
  float*    sout  = ws + 11534336;                    // [8,192,4096] f32
  float*    xr    = ws + 17825792;                    // [8,192,4096] f32
  short*    wb    = (short*)(ws + 24117248);          // bf16 weights
  float*    sums  = ws + 24295424;                    // 262144 f
  float*    carr  = ws + 24557568;                    // 131072 f
  short*    hid   = (short*)(ws + 24688640);          // [32768,768] bf16
  short*    xn2   = (short*)(ws + 37271552);          // [32768,192] bf16
  short*    wcatb = wb;            // [256,192] permuted
  short*    owb   = wb + 49152;    // [192,64]
  short*    w1b   = wb + 61440;    // [768,192]
  short*    w2b   = wb + 208896;   // [192,768]
  float*    out   = (float*)d_out;

  k_ln   <<<dim3(128, 8), 256, 0, stream>>>(x, ln1_g, ln1_b, ssm_g, ssm_b, xnb, xln1b);
  k_wconv<<<dim3(348),    256, 0, stream>>>(dt_w, B_w, C_w, xp_w, out_w, w1, w2, wb);
  k_proj <<<dim3(1024),   256, 0, stream>>>(xnb, wcatb, dt_b, xp_b, A_log, aA, bxc);
  k_scan1<<<dim3(256, 8),  64, 0, stream>>>(aA, bxc, sums);
  k_scan2<<<dim3(8),       64, 0, stream>>>(sums, carr);
  k_scan3<<<dim3(256, 8),  64, 0, stream>>>(aA, bxc, carr, yB);
  k_out  <<<dim3(512, 2), 256, 0, stream>>>(yB, owb, out_b, Dp, xln1b, sout);
  k_conv <<<dim3(192, 8), 256, 0, stream>>>(x, dw_w, bn_g, bn_b, bn_rm, bn_rv, sout, a_loc, a_ssm, xr);
  k_ln2  <<<dim3(128, 8), 256, 0, stream>>>(xr, ln2_g, ln2_b, xn2);
  k_gemm1<<<dim3(256, 6), 256, 0, stream>>>(xn2, w1b, b1, hid);
  k_gemm2<<<dim3(512, 2), 256, 0, stream>>>(hid, w2b, b2, xr, a_mlp, out);
}

// Round 8
// 290.245 us; speedup vs baseline: 1.0650x; 1.0650x over previous
//
#include <hip/hip_runtime.h>
#include <hip/hip_bf16.h>
#include <math.h>

// MambaBlock v8: v6 structure restored (LDS-staged GEMMs) + packed bf16 scan
// payload (aA f32 + (BX,C) packed) + wconv fused into prep kernel.

#define DEV static __device__ __forceinline__

constexpr int Bn = 8, Dm = 192, Ln = 4096, Sn = 64, Hd = 768;

typedef __attribute__((ext_vector_type(8))) short bf16x8;
typedef __attribute__((ext_vector_type(4))) float f32x4;

DEV float wave_sum(float v) {
#pragma unroll
  for (int off = 1; off < 64; off <<= 1) v += __shfl_xor(v, off);
  return v;
}

DEV short f2b(float x) {
  __hip_bfloat16 h = __float2bfloat16(x);
  return *(short*)&h;
}

DEV float b2f(short x) {
  __hip_bfloat16 h = *(__hip_bfloat16*)&x;
  return __bfloat162float(h);
}

// ---- K1: prep = transpose+ln1+ssm_ln (y<8) fused with weight->bf16 (y==8) --
__global__ __launch_bounds__(256) void k_prep(
    const float* __restrict__ x, const float* __restrict__ g1, const float* __restrict__ b1,
    const float* __restrict__ g2, const float* __restrict__ b2,
    short* __restrict__ xnb, short* __restrict__ xln1b,
    const float* __restrict__ dt_w, const float* __restrict__ B_w,
    const float* __restrict__ C_w, const float* __restrict__ xp_w,
    const float* __restrict__ out_w, const float* __restrict__ w1,
    const float* __restrict__ w2, short* __restrict__ wb) {
  __shared__ __align__(16) float tile[Dm * 65];
  int tid = threadIdx.x;
  if (blockIdx.y == 8) {
    // weight conversion: 89088 float4 groups over 64 blocks x 256 threads
    for (int i = blockIdx.x * 256 + tid; i < 89088; i += 64 * 256) {
      const float4* src;
      if (i < 3072)       src = (const float4*)dt_w + i;
      else if (i < 6144)  src = (const float4*)B_w + (i - 3072);
      else if (i < 9216)  src = (const float4*)C_w + (i - 6144);
      else if (i < 12288) src = (const float4*)xp_w + (i - 9216);
      else if (i < 15360) src = (const float4*)out_w + (i - 12288);
      else if (i < 52224) src = (const float4*)w1 + (i - 15360);
      else                src = (const float4*)w2 + (i - 52224);
      float4 v = *src;
      int o = i * 4;
      wb[o] = f2b(v.x); wb[o + 1] = f2b(v.y); wb[o + 2] = f2b(v.z); wb[o + 3] = f2b(v.w);
    }
    return;
  }
  int b = blockIdx.y, l0 = blockIdx.x * 64;
  const float* xb = x + (size_t)b * Dm * Ln;
  for (int i = tid; i < Dm * 16; i += 256) {
    int d = i >> 4, l4 = (i & 15) << 2;
    float4 v = *(const float4*)&xb[d * Ln + l0 + l4];
    tile[d * 65 + l4]     = v.x; tile[d * 65 + l4 + 1] = v.y;
    tile[d * 65 + l4 + 2] = v.z; tile[d * 65 + l4 + 3] = v.w;
  }
  __syncthreads();
  int lane = tid & 63, wv = tid >> 6;
  float ga0 = g1[lane], ga1 = g1[lane + 64], ga2 = g1[lane + 128];
  float bb0 = b1[lane], bb1 = b1[lane + 64], bb2 = b1[lane + 128];
  float gc0 = g2[lane], gc1 = g2[lane + 64], gc2 = g2[lane + 128];
  float bc0 = b2[lane], bc1 = b2[lane + 64], bc2 = b2[lane + 128];
  for (int li = wv; li < 64; li += 4) {
    float v0 = tile[lane * 65 + li], v1 = tile[(lane + 64) * 65 + li], v2 = tile[(lane + 128) * 65 + li];
    float s  = wave_sum(v0 + v1 + v2);
    float sq = wave_sum(v0 * v0 + v1 * v1 + v2 * v2);
    float m = s * (1.f / 192.f);
    float inv = rsqrtf(sq * (1.f / 192.f) - m * m + 1e-5f);
    float y0 = (v0 - m) * inv * ga0 + bb0;
    float y1 = (v1 - m) * inv * ga1 + bb1;
    float y2 = (v2 - m) * inv * ga2 + bb2;
    float s2  = wave_sum(y0 + y1 + y2);
    float sq2 = wave_sum(y0 * y0 + y1 * y1 + y2 * y2);
    float m2 = s2 * (1.f / 192.f);
    float inv2 = rsqrtf(sq2 * (1.f / 192.f) - m2 * m2 + 1e-5f);
    size_t base = ((size_t)b * Ln + l0 + li) * Dm;
    xln1b[base + lane]       = f2b(y0);
    xln1b[base + lane + 64]  = f2b(y1);
    xln1b[base + lane + 128] = f2b(y2);
    xnb[base + lane]       = f2b((y0 - m2) * inv2 * gc0 + bc0);
    xnb[base + lane + 64]  = f2b((y1 - m2) * inv2 * gc1 + bc1);
    xnb[base + lane + 128] = f2b((y2 - m2) * inv2 * gc2 + bc2);
  }
}

// ---- K2: MFMA proj GEMM (m-tile 64, LDS staged) + packed SSM epilogue ------
__global__ __launch_bounds__(256) void k_proj(
    const short* __restrict__ xnb, const short* __restrict__ wcat,
    const float* __restrict__ dt_b, const float* __restrict__ xp_b,
    const float* __restrict__ A_log, float* __restrict__ aA, unsigned* __restrict__ bxc) {
  __shared__ __align__(16) short As[64 * 72];
  __shared__ __align__(16) short Bs[256 * 72];
  int m0 = blockIdx.x * 64, tid = threadIdx.x;
  int lane = tid & 63, l16 = lane & 15, quad = lane >> 4, w = tid >> 6;
  f32x4 acc[16] = {};
  for (int kt = 0; kt < 3; kt++) {
    int kb = kt * 64;
    for (int i = tid; i < 512; i += 256) {
      int row = i >> 3, c8 = (i & 7) * 8;
      *(float4*)&As[row * 72 + c8] = *(const float4*)&xnb[(size_t)(m0 + row) * 192 + kb + c8];
    }
    for (int i = tid; i < 2048; i += 256) {
      int row = i >> 3, c8 = (i & 7) * 8;
      *(float4*)&Bs[row * 72 + c8] = *(const float4*)&wcat[(size_t)row * 192 + kb + c8];
    }
    __syncthreads();
#pragma unroll
    for (int ks = 0; ks < 2; ks++) {
      int ko = ks * 32 + quad * 8;
      bf16x8 a0 = *(const bf16x8*)&As[(w * 16 + l16) * 72 + ko];
#pragma unroll
      for (int nh = 0; nh < 2; nh++) {
        bf16x8 bfr[8];
#pragma unroll
        for (int j = 0; j < 8; j++) bfr[j] = *(const bf16x8*)&Bs[((nh * 8 + j) * 16 + l16) * 72 + ko];
#pragma unroll
        for (int j = 0; j < 8; j++)
          acc[nh * 8 + j] = __builtin_amdgcn_mfma_f32_16x16x32_bf16(a0, bfr[j], acc[nh * 8 + j], 0, 0, 0);
      }
    }
    __syncthreads();
  }
  float Av[4], dtbv[4], xpbv[4];
#pragma unroll
  for (int ni = 0; ni < 4; ni++) {
    int s = ni * 16 + l16;
    Av[ni] = -expf(A_log[s]); dtbv[ni] = dt_b[s]; xpbv[ni] = xp_b[s];
  }
#pragma unroll
  for (int r = 0; r < 4; r++) {
    int m = m0 + w * 16 + quad * 4 + r;
#pragma unroll
    for (int ni = 0; ni < 4; ni++) {
      int s = ni * 16 + l16;
      float z = acc[ni][r] + dtbv[ni];
      float sp = (z > 20.f) ? z : log1pf(expf(z));
      float delta = sp * 0.01f + 0.0001f;
      float bt  = acc[ni + 4][r];
      float ct  = acc[ni + 8][r];
      float xpv = acc[ni + 12][r] + xpbv[ni];
      float dA = fminf(fmaxf(delta * Av[ni], -10.f), -0.0001f);
      float Ae = fminf(fmaxf(expf(dA), 0.001f), 0.999f) + 1e-10f;
      aA[(size_t)m * 64 + s] = Ae;
      unsigned pk = (unsigned)(unsigned short)f2b(delta * bt * xpv)
                  | ((unsigned)(unsigned short)f2b(ct) << 16);
      bxc[(size_t)m * 64 + s] = pk;
    }
  }
}

// ---- K3: scan phase 1 (32-step chunks, packed input) -----------------------
__global__ __launch_bounds__(64) void k_scan1(const float* __restrict__ aA,
                                              const unsigned* __restrict__ bxc,
                                              float* __restrict__ sums) {
  int c = blockIdx.x, b = blockIdx.y, s = threadIdx.x;
  size_t r0 = (size_t)b * Ln + c * 32;
  const float* ap = aA + r0 * 64;
  const unsigned* bp = bxc + r0 * 64;
  float prodA = 1.f, h = 0.f;
  int t = 0;
  if (c == 0) { prodA = ap[s]; h = b2f((short)(bp[s] & 0xFFFF)); t = 1; }
#pragma unroll 4
  for (; t < 32; t++) {
    float a = ap[t * 64 + s];
    float bx = b2f((short)(bp[t * 64 + s] & 0xFFFF));
    h = a * (h + bx);
    prodA *= a;
  }
  int ci = b * 128 + c;
  sums[(ci * 2 + 0) * 64 + s] = prodA;
  sums[(ci * 2 + 1) * 64 + s] = h;
}

// ---- K4: scan phase 2 (carry chain over 128 chunks), one block per batch ---
__global__ __launch_bounds__(64) void k_scan2(const float* __restrict__ sums, float* __restrict__ carries) {
  int b = blockIdx.x, s = threadIdx.x;
  float cur = 0.f;
#pragma unroll 4
  for (int c = 0; c < 128; c++) {
    int ci = b * 128 + c;
    carries[ci * 64 + s] = cur;
    cur = sums[(ci * 2 + 0) * 64 + s] * cur + sums[(ci * 2 + 1) * 64 + s];
  }
}

// ---- K5: scan phase 3 (replay, packed input, y -> bf16) --------------------
__global__ __launch_bounds__(64) void k_scan3(const float* __restrict__ aA,
                                              const unsigned* __restrict__ bxc,
                                              const float* __restrict__ carries,
                                              short* __restrict__ y) {
  int c = blockIdx.x, b = blockIdx.y, s = threadIdx.x;
  size_t r0 = (size_t)b * Ln + c * 32;
  const float* ap = aA + r0 * 64;
  const unsigned* bp = bxc + r0 * 64;
  short* yo = y + r0 * 64;
  float h = carries[(b * 128 + c) * 64 + s];
  int t = 0;
  if (c == 0) {
    unsigned u = bp[s];
    h = b2f((short)(u & 0xFFFF));
    yo[s] = f2b(b2f((short)(u >> 16)) * h);
    t = 1;
  }
#pragma unroll 4
  for (; t < 32; t++) {
    unsigned u = bp[t * 64 + s];
    float a = ap[t * 64 + s];
    h = a * (h + b2f((short)(u & 0xFFFF)));
    yo[t * 64 + s] = f2b(b2f((short)(u >> 16)) * h);
  }
}

// ---- K6: MFMA out-proj (swapped, split-d, LDS staged): grid (512,2) --------
__global__ __launch_bounds__(256) void k_out(
    const short* __restrict__ y, const short* __restrict__ owb, const float* __restrict__ out_b,
    const float* __restrict__ Dp, const short* __restrict__ xln1b, float* __restrict__ sout) {
  __shared__ __align__(16) short As[96 * 72];
  __shared__ __align__(16) short Bs[64 * 72];
  int l0g = blockIdx.x * 64, d0 = blockIdx.y * 96, tid = threadIdx.x;
  int lane = tid & 63, l16 = lane & 15, quad = lane >> 4;
  int wm = (tid >> 6) >> 1, wn = (tid >> 6) & 1;
  f32x4 acc[3][2] = {};
  for (int i = tid; i < 768; i += 256) {
    int row = i >> 3, c8 = (i & 7) * 8;
    *(float4*)&As[row * 72 + c8] = *(const float4*)&owb[(d0 + row) * 64 + c8];
  }
  for (int i = tid; i < 512; i += 256) {
    int row = i >> 3, c8 = (i & 7) * 8;
    *(float4*)&Bs[row * 72 + c8] = *(const float4*)&y[(size_t)(l0g + row) * 64 + c8];
  }
  __syncthreads();
#pragma unroll
  for (int ks = 0; ks < 2; ks++) {
    int ko = ks * 32 + quad * 8;
    bf16x8 a[3], b[2];
#pragma unroll
    for (int mi = 0; mi < 3; mi++) a[mi] = *(const bf16x8*)&As[(wm * 48 + mi * 16 + l16) * 72 + ko];
#pragma unroll
    for (int ni = 0; ni < 2; ni++) b[ni] = *(const bf16x8*)&Bs[(wn * 32 + ni * 16 + l16) * 72 + ko];
#pragma unroll
    for (int mi = 0; mi < 3; mi++)
#pragma unroll
      for (int ni = 0; ni < 2; ni++)
        acc[mi][ni] = __builtin_amdgcn_mfma_f32_16x16x32_bf16(a[mi], b[ni], acc[mi][ni], 0, 0, 0);
  }
  int bb = l0g >> 12;
#pragma unroll
  for (int mi = 0; mi < 3; mi++)
#pragma unroll
    for (int r = 0; r < 4; r++) {
      int d = d0 + wm * 48 + mi * 16 + quad * 4 + r;
      float ob = out_b[d];
      float dc = fminf(fmaxf(Dp[d], -2.f), 2.f);
#pragma unroll
      for (int ni = 0; ni < 2; ni++) {
        int l = l0g + wn * 32 + ni * 16 + l16;
        float v = acc[mi][ni][r] + ob;
        if (dc != 0.f) v += dc * b2f(xln1b[(size_t)l * 192 + d]);
        sout[((size_t)bb * Dm + d) * Ln + (l & 4095)] = v;
      }
    }
}

// ---- K7: depthwise conv 3x3 + BN + residual combine -> xr (NCHW) -----------
__global__ __launch_bounds__(256) void k_conv(
    const float* __restrict__ x, const float* __restrict__ dw,
    const float* __restrict__ bn_g, const float* __restrict__ bn_b,
    const float* __restrict__ bn_rm, const float* __restrict__ bn_rv,
    const float* __restrict__ sout, const float* __restrict__ a_loc,
    const float* __restrict__ a_ssm, float* __restrict__ xr) {
  __shared__ __align__(16) float xs[64 * 64];
  int d = blockIdx.x, b = blockIdx.y, tid = threadIdx.x;
  const float* xp = x + ((size_t)b * Dm + d) * Ln;
  for (int i = tid; i < 1024; i += 256) ((float4*)xs)[i] = ((const float4*)xp)[i];
  __syncthreads();
  float w[9];
#pragma unroll
  for (int k = 0; k < 9; k++) w[k] = dw[d * 9 + k];
  float scale = bn_g[d] * rsqrtf(bn_rv[d] + 1e-5f);
  float rm = bn_rm[d], bb = bn_b[d];
  float al = a_loc[0], as_ = a_ssm[0];
  const float* sp = sout + ((size_t)b * Dm + d) * Ln;
  float* xo = xr + ((size_t)b * Dm + d) * Ln;
  for (int i = tid; i < 4096; i += 256) {
    int h = i >> 6, wc = i & 63;
    float acc = 0.f;
#pragma unroll
    for (int kh = 0; kh < 3; kh++) {
      int hh = h + kh - 1;
      if (hh < 0 || hh >= 64) continue;
#pragma unroll
      for (int kw = 0; kw < 3; kw++) {
        int ww2 = wc + kw - 1;
        if (ww2 < 0 || ww2 >= 64) continue;
        acc += xs[hh * 64 + ww2] * w[kh * 3 + kw];
      }
    }
    float xl = (acc - rm) * scale + bb;
    xo[i] = xs[i] + al * xl + as_ * sp[i];
  }
}

// ---- K8: ln2 -> bf16 xn2 [B*L, 192] row-major ------------------------------
__global__ __launch_bounds__(256) void k_ln2(
    const float* __restrict__ xr, const float* __restrict__ g, const float* __restrict__ bb,
    short* __restrict__ xn2) {
  __shared__ __align__(16) float tile[Dm * 65];
  int b = blockIdx.y, l0 = blockIdx.x * 64, tid = threadIdx.x;
  const float* xb = xr + (size_t)b * Dm * Ln;
  for (int i = tid; i < Dm * 16; i += 256) {
    int d = i >> 4, l4 = (i & 15) << 2;
    float4 v = *(const float4*)&xb[d * Ln + l0 + l4];
    tile[d * 65 + l4]     = v.x; tile[d * 65 + l4 + 1] = v.y;
    tile[d * 65 + l4 + 2] = v.z; tile[d * 65 + l4 + 3] = v.w;
  }
  __syncthreads();
  int lane = tid & 63, wv = tid >> 6;
  float g0 = g[lane], g1v = g[lane + 64], g2v = g[lane + 128];
  float b0 = bb[lane], b1v = bb[lane + 64], b2v = bb[lane + 128];
  for (int li = wv; li < 64; li += 4) {
    float v0 = tile[lane * 65 + li], v1 = tile[(lane + 64) * 65 + li], v2 = tile[(lane + 128) * 65 + li];
    float s  = wave_sum(v0 + v1 + v2);
    float sq = wave_sum(v0 * v0 + v1 * v1 + v2 * v2);
    float m = s * (1.f / 192.f);
    float inv = rsqrtf(sq * (1.f / 192.f) - m * m + 1e-5f);
    size_t base = ((size_t)b * Ln + l0 + li) * Dm;
    xn2[base + lane]       = f2b((v0 - m) * inv * g0 + b0);
    xn2[base + lane + 64]  = f2b((v1 - m) * inv * g1v + b1v);
    xn2[base + lane + 128] = f2b((v2 - m) * inv * g2v + b2v);
  }
}

// ---- K9: MFMA GEMM1: hid = gelu(xn2 @ w1^T + b1), LDS-staged coalesced out -
__global__ __launch_bounds__(256) void k_gemm1(
    const short* __restrict__ xn2, const short* __restrict__ w1b,
    const float* __restrict__ b1h, short* __restrict__ hid) {
  __shared__ __align__(16) short smem[2 * 128 * 88];  // As | Bs; reused as C-stage
  short* As = smem;
  short* Bs = smem + 128 * 88;
  int m0 = blockIdx.x * 128, n0 = blockIdx.y * 128, tid = threadIdx.x;
  int lane = tid & 63, l16 = lane & 15, quad = lane >> 4;
  int wm = (tid >> 6) >> 1, wn = (tid >> 6) & 1;
  f32x4 acc[4][4] = {};
  for (int kt = 0; kt < 3; kt++) {
    int kb = kt * 64;
    for (int i = tid; i < 1024; i += 256) {
      int row = i >> 3, c8 = (i & 7) * 8;
      *(float4*)&As[row * 88 + c8] = *(const float4*)&xn2[(size_t)(m0 + row) * 192 + kb + c8];
      *(float4*)&Bs[row * 88 + c8] = *(const float4*)&w1b[(size_t)(n0 + row) * 192 + kb + c8];
    }
    __syncthreads();
#pragma unroll
    for (int ks = 0; ks < 2; ks++) {
      int ko = ks * 32 + quad * 8;
      bf16x8 a[4], b[4];
#pragma unroll
      for (int mi = 0; mi < 4; mi++) a[mi] = *(const bf16x8*)&As[(wm * 64 + mi * 16 + l16) * 88 + ko];
#pragma unroll
      for (int ni = 0; ni < 4; ni++) b[ni] = *(const bf16x8*)&Bs[(wn * 64 + ni * 16 + l16) * 88 + ko];
#pragma unroll
      for (int mi = 0; mi < 4; mi++)
#pragma unroll
        for (int ni = 0; ni < 4; ni++)
          acc[mi][ni] = __builtin_amdgcn_mfma_f32_16x16x32_bf16(a[mi], b[ni], acc[mi][ni], 0, 0, 0);
    }
    __syncthreads();
  }
  short* Cs = smem;
  float bias4[4];
#pragma unroll
  for (int ni = 0; ni < 4; ni++) bias4[ni] = b1h[n0 + wn * 64 + ni * 16 + l16];
#pragma unroll
  for (int mi = 0; mi < 4; mi++)
#pragma unroll
    for (int ni = 0; ni < 4; ni++) {
      int n = wn * 64 + ni * 16 + l16;
#pragma unroll
      for (int r = 0; r < 4; r++) {
        int m = wm * 64 + mi * 16 + quad * 4 + r;
        float v = acc[mi][ni][r] + bias4[ni];
        float g = 0.5f * v * (1.f + erff(v * 0.70710678118f));
        Cs[m * 136 + n] = f2b(g);
      }
    }
  __syncthreads();
  for (int i = tid; i < 2048; i += 256) {
    int m = i >> 4, ch = i & 15;
    *(float4*)&hid[(size_t)(m0 + m) * 768 + n0 + ch * 8] = *(const float4*)&Cs[m * 136 + ch * 8];
  }
}

// ---- K10: MFMA GEMM2 (swapped, split-d, LDS staged): grid (512,2) ----------
__global__ __launch_bounds__(256) void k_gemm2(
    const short* __restrict__ hid, const short* __restrict__ w2b,
    const float* __restrict__ b2o, const float* __restrict__ xr,
    const float* __restrict__ am, float* __restrict__ out) {
  __shared__ __align__(16) short Wt[96 * 88];
  __shared__ __align__(16) short Ht[64 * 88];
  int l0g = blockIdx.x * 64, d0 = blockIdx.y * 96, tid = threadIdx.x;
  int lane = tid & 63, l16 = lane & 15, quad = lane >> 4;
  int wm = (tid >> 6) >> 1, wn = (tid >> 6) & 1;
  f32x4 acc[3][2] = {};
  for (int kt = 0; kt < 12; kt++) {
    int kb = kt * 64;
    for (int i = tid; i < 768; i += 256) {
      int row = i >> 3, c8 = (i & 7) * 8;
      *(float4*)&Wt[row * 88 + c8] = *(const float4*)&w2b[(size_t)(d0 + row) * 768 + kb + c8];
    }
    for (int i = tid; i < 512; i += 256) {
      int row = i >> 3, c8 = (i & 7) * 8;
      *(float4*)&Ht[row * 88 + c8] = *(const float4*)&hid[(size_t)(l0g + row) * 768 + kb + c8];
    }
    __syncthreads();
#pragma unroll
    for (int ks = 0; ks < 2; ks++) {
      int ko = ks * 32 + quad * 8;
      bf16x8 a[3], b[2];
#pragma unroll
      for (int mi = 0; mi < 3; mi++) a[mi] = *(const bf16x8*)&Wt[(wm * 48 + mi * 16 + l16) * 88 + ko];
#pragma unroll
      for (int ni = 0; ni < 2; ni++) b[ni] = *(const bf16x8*)&Ht[(wn * 32 + ni * 16 + l16) * 88 + ko];
#pragma unroll
      for (int mi = 0; mi < 3; mi++)
#pragma unroll
        for (int ni = 0; ni < 2; ni++)
          acc[mi][ni] = __builtin_amdgcn_mfma_f32_16x16x32_bf16(a[mi], b[ni], acc[mi][ni], 0, 0, 0);
    }
    __syncthreads();
  }
  float alpha = am[0];
#pragma unroll
  for (int mi = 0; mi < 3; mi++)
#pragma unroll
    for (int r = 0; r < 4; r++) {
      int d = d0 + wm * 48 + mi * 16 + quad * 4 + r;
      float bias = b2o[d];
#pragma unroll
      for (int ni = 0; ni < 2; ni++) {
        int lg = l0g + wn * 32 + ni * 16 + l16;
        size_t idx = ((size_t)(lg >> 12) * Dm + d) * Ln + (lg & 4095);
        out[idx] = xr[idx] + alpha * (acc[mi][ni][r] + bias);
      }
    }
}

extern "C" void kernel_launch(void* const* d_in, const int* in_sizes, int n_in,
                              void* d_out, int out_size, void* d_ws, size_t ws_size,
                              hipStream_t stream) {
  (void)in_sizes; (void)n_in; (void)out_size; (void)ws_size;
  const float* x     = (const float*)d_in[0];
  const float* ln1_g = (const float*)d_in[1];
  const float* ln1_b = (const float*)d_in[2];
  const float* ln2_g = (const float*)d_in[3];
  const float* ln2_b = (const float*)d_in[4];
  const float* dw_w  = (const float*)d_in[5];
  const float* bn_g  = (const float*)d_in[6];
  const float* bn_b  = (const float*)d_in[7];
  const float* bn_rm = (const float*)d_in[8];
  const float* bn_rv = (const float*)d_in[9];
  const float* ssm_g = (const float*)d_in[10];
  const float* ssm_b = (const float*)d_in[11];
  const float* xp_w  = (const float*)d_in[12];
  const float* xp_b  = (const float*)d_in[13];
  const float* dt_w  = (const float*)d_in[14];
  const float* dt_b  = (const float*)d_in[15];
  const float* A_log = (const float*)d_in[16];
  const float* B_w   = (const float*)d_in[17];
  const float* C_w   = (const float*)d_in[18];
  const float* Dp    = (const float*)d_in[19];
  const float* out_w = (const float*)d_in[20];
  const float* out_b = (const float*)d_in[21];
  const float* w1    = (const float*)d_in[22];
  const float* b1    = (const float*)d_in[23];
  const float* w2    = (const float*)d_in[24];
  const float* b2    = (const float*)d_in[25];
  const float* a_loc = (const float*)d_in[26];
  const float* a_ssm = (const float*)d_in[27];
  const float* a_mlp = (const float*)d_in[28];

  float* ws = (float*)d_ws;
  short*    xnb   = (short*)ws;                    // [32768,192] bf16
  short*    xln1b = (short*)(ws + 3145728);        // [32768,192] bf16
  float*    aA    = ws + 6291456;                  // [32768,64] f32
  unsigned* bxc   = (unsigned*)(ws + 8388608);     // [32768,64] packed bf16x2
  short*    yB    = (short*)(ws + 10485760);       // [32768,64] bf16
  float*    sout  = ws + 11534336;                 // [8,192,4096] f32
  float*    xr    = ws + 17825792;                 // [8,192,4096] f32
  short*    wb    = (short*)(ws + 24117248);       // bf16 weights (356352 sh)
  float*    sums  = ws + 24829952;                 // 131072 f
  float*    carr  = ws + 24961024;                 // 65536 f
  short*    xn2   = (short*)(ws + 25026560);       // [32768,192] bf16
  short*    hid   = (short*)(ws + 28172288);       // [32768,768] bf16
  short*    wcatb = wb;            // [256,192] = dt|B|C|xp rows
  short*    owb   = wb + 49152;    // [192,64]
  short*    w1b   = wb + 61440;    // [768,192]
  short*    w2b   = wb + 208896;   // [192,768]
  float*    out   = (float*)d_out;

  k_prep <<<dim3(64, 9),  256, 0, stream>>>(x, ln1_g, ln1_b, ssm_g, ssm_b, xnb, xln1b,
                                            dt_w, B_w, C_w, xp_w, out_w, w1, w2, wb);
  k_proj <<<dim3(512),    256, 0, stream>>>(xnb, wcatb, dt_b, xp_b, A_log, aA, bxc);
  k_scan1<<<dim3(128, 8),  64, 0, stream>>>(aA, bxc, sums);
  k_scan2<<<dim3(8),       64, 0, stream>>>(sums, carr);
  k_scan3<<<dim3(128, 8),  64, 0, stream>>>(aA, bxc, carr, yB);
  k_out  <<<dim3(512, 2), 256, 0, stream>>>(yB, owb, out_b, Dp, xln1b, sout);
  k_conv <<<dim3(192, 8), 256, 0, stream>>>(x, dw_w, bn_g, bn_b, bn_rm, bn_rv, sout, a_loc, a_ssm, xr);
  k_ln2  <<<dim3(64, 8),  256, 0, stream>>>(xr, ln2_g, ln2_b, xn2);
  k_gemm1<<<dim3(256, 6), 256, 0, stream>>>(xn2, w1b, b1, hid);
  k_gemm2<<<dim3(512, 2), 256, 0, stream>>>(hid, w2b, b2, xr, a_mlp, out);
}